// Round 11
// baseline (107.488 us; speedup 1.0000x reference)
//
#include <hip/hip_runtime.h>

// Problem constants (static per the reference file)
#define N_TOK 16384          // S*B tokens
#define E_EXP 64             // experts
#define H_DIM 2048           // hidden
#define NV4   (H_DIM / 4)    // float4 per row = 512
#define NCHUNK (N_TOK / 64)  // 256 chunks of 64 tokens (one wave each)
#define RS_BLOCKS (NCHUNK/4) // 64 route blocks, 4 chunk-waves each

typedef float f32x4 __attribute__((ext_vector_type(4)));

// ---------------------------------------------------------------------------
// Kernel 1 (route+scan fused): 64 blocks x 256 threads; wave w of block b owns
// chunk c = b*4+w (lane = token within chunk). Route is the proven r7 wave
// ballot pass. Then: device-scope fence -> atomic ticket -> the LAST block to
// finish runs the 256-thread scan inline (quarter-partials -> shfl exclusive
// scan over experts -> in-place fused base[c][e]). Saves the scan kernel's
// launch + standalone latency. Ticket counter is zeroed each call by a 4-byte
// hipMemsetAsync (deterministic; order-independent by construction).
// ---------------------------------------------------------------------------
__global__ __launch_bounds__(256)
void route_scan_kernel(const f32x4* __restrict__ probs4,
                       uint4* __restrict__ recs,        // [N] {e0|e1<<16, r0|r1<<16, ps, 0}
                       int*   __restrict__ hist,        // [NCHUNK][E] -> base
                       float* __restrict__ tpe_out,     // [E]
                       unsigned int* __restrict__ done_ctr) {
    const int wave = threadIdx.x >> 6;
    const int lane = threadIdx.x & 63;
    const int c = blockIdx.x * 4 + wave;
    const int t = c * 64 + lane;

    // ---- route (per-wave, independent) ----
    const f32x4* pr = probs4 + (size_t)t * (E_EXP / 4);
    int e0 = -1, e1 = -1;
    float ps = 0.0f;
    #pragma unroll
    for (int j = 0; j < E_EXP / 4; ++j) {
        const f32x4 q = pr[j];
        if (q.x > 0.0f) { if (e0 < 0) e0 = 4*j+0; else e1 = 4*j+0; ps += q.x; }
        if (q.y > 0.0f) { if (e0 < 0) e0 = 4*j+1; else e1 = 4*j+1; ps += q.y; }
        if (q.z > 0.0f) { if (e0 < 0) e0 = 4*j+2; else e1 = 4*j+2; ps += q.z; }
        if (q.w > 0.0f) { if (e0 < 0) e0 = 4*j+3; else e1 = 4*j+3; ps += q.w; }
    }

    const unsigned long long lt = (1ULL << lane) - 1ULL;
    int r0 = 0, r1 = 0, hval = 0;
    #pragma unroll 8
    for (int e = 0; e < E_EXP; ++e) {
        const bool hit = (e == e0) || (e == e1);
        const unsigned long long m = __ballot(hit);
        const int below = __popcll(m & lt);
        if (e == e0) r0 = below;
        if (e == e1) r1 = below;
        if (lane == e) hval = __popcll(m);
    }
    hist[c * E_EXP + lane] = hval;
    recs[t] = make_uint4((unsigned)e0 | ((unsigned)e1 << 16),
                         (unsigned)r0 | ((unsigned)r1 << 16),
                         __float_as_uint(ps), 0u);

    // ---- last-block election (decoupled-lookback pattern) ----
    __threadfence();                       // release: hist/recs visible device-wide
    __syncthreads();
    __shared__ int s_last;
    if (threadIdx.x == 0) {
        const unsigned tk = atomicAdd(done_ctr, 1u);   // device-scope
        s_last = (tk == RS_BLOCKS - 1);
    }
    __syncthreads();
    if (!s_last) return;
    __threadfence();                       // acquire: see all blocks' hist

    // ---- scan (256 threads: q = quarter, e = expert) ----
    __shared__ int part[4][E_EXP];
    __shared__ int offs[E_EXP];
    const int tid = threadIdx.x;
    const int q = tid >> 6;
    const int e = tid & 63;

    int acc = 0;
    #pragma unroll 16
    for (int j = 0; j < 64; ++j) acc += hist[(q * 64 + j) * E_EXP + e];
    part[q][e] = acc;
    __syncthreads();

    if (tid < 64) {
        const int tot = part[0][tid] + part[1][tid] + part[2][tid] + part[3][tid];
        tpe_out[tid] = (float)tot;
        int x = tot;
        #pragma unroll
        for (int d = 1; d < 64; d <<= 1) {
            const int y = __shfl_up(x, d, 64);
            if (tid >= d) x += y;
        }
        offs[tid] = x - tot;
    }
    __syncthreads();

    int start = offs[e];
    for (int qq = 0; qq < q; ++qq) start += part[qq][e];
    #pragma unroll 16
    for (int j = 0; j < 64; ++j) {
        const int idx = (q * 64 + j) * E_EXP + e;
        const int v = hist[idx];
        hist[idx] = start;
        start += v;
    }
}

// ---------------------------------------------------------------------------
// Kernel 2 (dispatch): EXACT round-7 winner. One wave per token, cached hs
// loads (hs = 128 MB stays LLC-resident across graph replays), all three
// output streams non-temporal (never re-read; don't evict hs). Full 8KB row
// into registers, one contiguous 8KB nt burst per stream:
//   out_total[t] = hs[t] * (p0+p1); permuted[m0] = permuted[m1] = hs[t]
// ---------------------------------------------------------------------------
__global__ __launch_bounds__(256)
void dispatch_kernel(const f32x4* __restrict__ hs4,
                     const uint4* __restrict__ recs,
                     const int*   __restrict__ base,   // [NCHUNK][E]
                     f32x4* __restrict__ out4,         // [N][NV4]
                     f32x4* __restrict__ perm4) {      // [M][NV4]
    const int wave = threadIdx.x >> 6;
    const int lane = threadIdx.x & 63;
    const int t = (blockIdx.x << 2) | wave;
    const int c = t >> 6;

    const uint4 rec = recs[t];                  // wave-uniform 16B
    const int e0 = (int)(rec.x & 0xffffu), e1 = (int)(rec.x >> 16);
    const int m0 = base[c * E_EXP + e0] + (int)(rec.y & 0xffffu);
    const int m1 = base[c * E_EXP + e1] + (int)(rec.y >> 16);
    const float ps = __uint_as_float(rec.z);

    const f32x4* __restrict__ src = hs4 + (size_t)t * NV4 + lane;
    f32x4 v[8];
    #pragma unroll
    for (int i = 0; i < 8; ++i) v[i] = src[i * 64];   // cached: hs stays in LLC

    f32x4* __restrict__ d0 = out4 + (size_t)t * NV4 + lane;
    #pragma unroll
    for (int i = 0; i < 8; ++i) __builtin_nontemporal_store(v[i] * ps, &d0[i * 64]);

    f32x4* __restrict__ dp0 = perm4 + (size_t)m0 * NV4 + lane;
    #pragma unroll
    for (int i = 0; i < 8; ++i) __builtin_nontemporal_store(v[i], &dp0[i * 64]);

    f32x4* __restrict__ dp1 = perm4 + (size_t)m1 * NV4 + lane;
    #pragma unroll
    for (int i = 0; i < 8; ++i) __builtin_nontemporal_store(v[i], &dp1[i * 64]);
}

// ---------------------------------------------------------------------------
extern "C" void kernel_launch(void* const* d_in, const int* in_sizes, int n_in,
                              void* d_out, int out_size, void* d_ws, size_t ws_size,
                              hipStream_t stream) {
    const float* hs    = (const float*)d_in[0];   // [S,B,H] f32
    const float* probs = (const float*)d_in[1];   // [N,E]   f32
    // d_in[2] (routing_map) unused: probs>0 encodes it exactly.

    float* out      = (float*)d_out;
    float* out_tot  = out;                                   // [N*H]
    float* out_tpe  = out + (size_t)N_TOK * H_DIM;           // [E]
    float* out_perm = out_tpe + E_EXP;                       // [M*H]

    uint4* recs = (uint4*)d_ws;                                          // 256 KB
    int*   hist = (int*)((char*)d_ws + (size_t)N_TOK * sizeof(uint4));   // 64 KB
    unsigned int* done_ctr = (unsigned int*)(hist + NCHUNK * E_EXP);     // 4 B

    hipMemsetAsync(done_ctr, 0, sizeof(unsigned int), stream);
    route_scan_kernel<<<RS_BLOCKS, 256, 0, stream>>>((const f32x4*)probs, recs, hist,
                                                     out_tpe, done_ctr);
    dispatch_kernel  <<<N_TOK/4,   256, 0, stream>>>((const f32x4*)hs, recs, hist,
                                                     (f32x4*)out_tot, (f32x4*)out_perm);
}

// Round 12
// 95.510 us; speedup vs baseline: 1.1254x; 1.1254x over previous
//
#include <hip/hip_runtime.h>

// Problem constants (static per the reference file)
#define N_TOK 16384          // S*B tokens
#define E_EXP 64             // experts
#define H_DIM 2048           // hidden
#define NV4   (H_DIM / 4)    // float4 per row = 512
#define NCHUNK (N_TOK / 64)  // 256 chunks of 64 tokens (one wave each)

typedef float f32x4 __attribute__((ext_vector_type(4)));

// ---------------------------------------------------------------------------
// ROUND-7 CONFIGURATION (measured optimum of the session's search space).
// Cache-policy map (measured): cached-load/nt-store = 95.1 us (this);
// nt/nt = 122; cached/plain = 125; mixed = 98; dest-major = 135; fused = 107.
// Mechanism: hs (128 MB) stays Infinity-Cache-resident across graph replays;
// all output streams (384 MB, written once, never read) bypass the LLC via
// nt stores so they cannot evict hs. Dispatch then moves ~512 MB aggregate
// (128 LLC-read + 384 HBM-write) in ~85 us ~= 6.0 TB/s ~= 95% of the
// achievable 6.3 TB/s ceiling.
// ---------------------------------------------------------------------------

// ---------------------------------------------------------------------------
// Kernel 1 (route): one wave per 64-token chunk. Lane = token within chunk.
// Lane reads its probs row as 16 float4, finds the two positive entries
// (softmax over top-2 is strictly positive => exactly two), then a wave-uniform
// 64-iteration ballot loop produces stable in-chunk ranks + per-chunk histogram.
// ---------------------------------------------------------------------------
__global__ __launch_bounds__(64)
void route_kernel(const f32x4* __restrict__ probs4,
                  uint4* __restrict__ recs,      // [N] {e0|e1<<16, r0|r1<<16, ps, 0}
                  int*   __restrict__ hist) {    // [NCHUNK][E]
    const int c    = blockIdx.x;
    const int lane = threadIdx.x;
    const int t    = c * 64 + lane;

    const f32x4* pr = probs4 + (size_t)t * (E_EXP / 4);
    int e0 = -1, e1 = -1;
    float ps = 0.0f;
    #pragma unroll
    for (int j = 0; j < E_EXP / 4; ++j) {
        const f32x4 q = pr[j];
        if (q.x > 0.0f) { if (e0 < 0) e0 = 4*j+0; else e1 = 4*j+0; ps += q.x; }
        if (q.y > 0.0f) { if (e0 < 0) e0 = 4*j+1; else e1 = 4*j+1; ps += q.y; }
        if (q.z > 0.0f) { if (e0 < 0) e0 = 4*j+2; else e1 = 4*j+2; ps += q.z; }
        if (q.w > 0.0f) { if (e0 < 0) e0 = 4*j+3; else e1 = 4*j+3; ps += q.w; }
    }

    const unsigned long long lt = (1ULL << lane) - 1ULL;
    int r0 = 0, r1 = 0, hval = 0;
    #pragma unroll 8
    for (int e = 0; e < E_EXP; ++e) {
        const bool hit = (e == e0) || (e == e1);
        const unsigned long long m = __ballot(hit);
        const int below = __popcll(m & lt);
        if (e == e0) r0 = below;
        if (e == e1) r1 = below;
        if (lane == e) hval = __popcll(m);
    }
    hist[c * E_EXP + lane] = hval;           // coalesced 256B store
    recs[t] = make_uint4((unsigned)e0 | ((unsigned)e1 << 16),
                         (unsigned)r0 | ((unsigned)r1 << 16),
                         __float_as_uint(ps), 0u);
}

// ---------------------------------------------------------------------------
// Kernel 2 (scan): one block, 256 threads. tid -> (q = quarter of chunk axis,
// e = expert). Quarter-partials -> wave-0 shfl exclusive scan over experts ->
// in-place fused exclusive base: base[c][e] = offs[e] + sum_{c'<c} hist[c'][e].
// ---------------------------------------------------------------------------
__global__ __launch_bounds__(256)
void scan_kernel(int* __restrict__ hist,          // in: hist, out: base
                 float* __restrict__ tpe_out) {   // [E]
    __shared__ int part[4][E_EXP];
    __shared__ int offs[E_EXP];
    const int tid = threadIdx.x;
    const int q = tid >> 6;
    const int e = tid & 63;

    int acc = 0;
    #pragma unroll 16
    for (int j = 0; j < 64; ++j) acc += hist[(q * 64 + j) * E_EXP + e];
    part[q][e] = acc;
    __syncthreads();

    if (tid < 64) {
        const int tot = part[0][tid] + part[1][tid] + part[2][tid] + part[3][tid];
        tpe_out[tid] = (float)tot;
        int x = tot;
        #pragma unroll
        for (int d = 1; d < 64; d <<= 1) {
            const int y = __shfl_up(x, d, 64);
            if (tid >= d) x += y;
        }
        offs[tid] = x - tot;
    }
    __syncthreads();

    int start = offs[e];
    for (int qq = 0; qq < q; ++qq) start += part[qq][e];
    #pragma unroll 16
    for (int j = 0; j < 64; ++j) {
        const int idx = (q * 64 + j) * E_EXP + e;
        const int v = hist[idx];
        hist[idx] = start;
        start += v;
    }
}

// ---------------------------------------------------------------------------
// Kernel 3 (dispatch, the BW kernel): ONE WAVE PER TOKEN, no barriers.
// hs loads NORMAL (cached -> LLC-resident across replays); all output stores
// NON-TEMPORAL (never re-read; don't evict hs). Full 8KB row into registers,
// then one contiguous 8KB nt burst per stream:
//   out_total[t] = hs[t] * (p0+p1); permuted[m0] = permuted[m1] = hs[t]
// ---------------------------------------------------------------------------
__global__ __launch_bounds__(256)
void dispatch_kernel(const f32x4* __restrict__ hs4,
                     const uint4* __restrict__ recs,
                     const int*   __restrict__ base,   // [NCHUNK][E]
                     f32x4* __restrict__ out4,         // [N][NV4]
                     f32x4* __restrict__ perm4) {      // [M][NV4]
    const int wave = threadIdx.x >> 6;
    const int lane = threadIdx.x & 63;
    const int t = (blockIdx.x << 2) | wave;
    const int c = t >> 6;

    const uint4 rec = recs[t];                  // wave-uniform 16B
    const int e0 = (int)(rec.x & 0xffffu), e1 = (int)(rec.x >> 16);
    const int m0 = base[c * E_EXP + e0] + (int)(rec.y & 0xffffu);
    const int m1 = base[c * E_EXP + e1] + (int)(rec.y >> 16);
    const float ps = __uint_as_float(rec.z);

    const f32x4* __restrict__ src = hs4 + (size_t)t * NV4 + lane;
    f32x4 v[8];
    #pragma unroll
    for (int i = 0; i < 8; ++i) v[i] = src[i * 64];   // cached: hs stays in LLC

    f32x4* __restrict__ d0 = out4 + (size_t)t * NV4 + lane;
    #pragma unroll
    for (int i = 0; i < 8; ++i) __builtin_nontemporal_store(v[i] * ps, &d0[i * 64]);

    f32x4* __restrict__ dp0 = perm4 + (size_t)m0 * NV4 + lane;
    #pragma unroll
    for (int i = 0; i < 8; ++i) __builtin_nontemporal_store(v[i], &dp0[i * 64]);

    f32x4* __restrict__ dp1 = perm4 + (size_t)m1 * NV4 + lane;
    #pragma unroll
    for (int i = 0; i < 8; ++i) __builtin_nontemporal_store(v[i], &dp1[i * 64]);
}

// ---------------------------------------------------------------------------
extern "C" void kernel_launch(void* const* d_in, const int* in_sizes, int n_in,
                              void* d_out, int out_size, void* d_ws, size_t ws_size,
                              hipStream_t stream) {
    const float* hs    = (const float*)d_in[0];   // [S,B,H] f32
    const float* probs = (const float*)d_in[1];   // [N,E]   f32
    // d_in[2] (routing_map) unused: probs>0 encodes it exactly.

    float* out      = (float*)d_out;
    float* out_tot  = out;                                   // [N*H]
    float* out_tpe  = out + (size_t)N_TOK * H_DIM;           // [E]
    float* out_perm = out_tpe + E_EXP;                       // [M*H]

    uint4* recs = (uint4*)d_ws;                              // 256 KB
    int*   hist = (int*)((char*)d_ws + (size_t)N_TOK * sizeof(uint4)); // 64 KB

    route_kernel   <<<NCHUNK,  64,  0, stream>>>((const f32x4*)probs, recs, hist);
    scan_kernel    <<<1,       256, 0, stream>>>(hist, out_tpe);
    dispatch_kernel<<<N_TOK/4, 256, 0, stream>>>((const f32x4*)hs, recs, hist,
                                                 (f32x4*)out_tot, (f32x4*)out_perm);
}